// Round 7
// baseline (727.859 us; speedup 1.0000x reference)
//
#include <hip/hip_runtime.h>
#include <stdint.h>

typedef unsigned long long u64;
typedef unsigned u32;
typedef float __attribute__((ext_vector_type(4))) f4raw;

#define K 27
#define S 258
#define ENCMAX (4 * S * S * S)        // 68,694,048 possible keys

// ---- manual grid barrier (used at <=768 co-resident blocks only) -----------
__device__ __forceinline__ void gbar(int* cnt, int nblk) {
    __syncthreads();
    if (threadIdx.x == 0) {
        __threadfence();
        __hip_atomic_fetch_add(cnt, 1, __ATOMIC_RELEASE, __HIP_MEMORY_SCOPE_AGENT);
        while (__hip_atomic_load(cnt, __ATOMIC_RELAXED, __HIP_MEMORY_SCOPE_AGENT) < nblk)
            __builtin_amdgcn_s_sleep(2);
        (void)__hip_atomic_load(cnt, __ATOMIC_ACQUIRE, __HIP_MEMORY_SCOPE_AGENT);
        __threadfence();
    }
    __syncthreads();
}

// ---------- pass 1: presence bits + exact dup bits (round-1 exact) ----------
__global__ void k_mark(const int* __restrict__ si, int N,
                       u64* __restrict__ bits, u64* __restrict__ dupb) {
    int idx = blockIdx.x * blockDim.x + threadIdx.x;
    if (idx >= N * 9) return;
    int n = idx / 9, run = idx - n * 9;
    int ox = run / 3, oy = run - ox * 3;
    int b = si[n], x = si[N + n], y = si[2 * N + n], z = si[3 * N + n];
    unsigned enc0 = (unsigned)(((b * S + x + ox) * S + (y + oy)) * S + z);
    unsigned w = enc0 >> 6; int bit = enc0 & 63;
    u64 m1 = 7ull << bit;
    u64 old = atomicOr(&bits[w], m1);
    u64 d1 = old & m1;
    if (d1) atomicOr(&dupb[w], d1);                 // rare (~55k total)
    if (bit > 61) {
        u64 m2 = 7ull >> (64 - bit);
        u64 old2 = atomicOr(&bits[w + 1], m2);
        u64 d2 = old2 & m2;
        if (d2) atomicOr(&dupb[w + 1], d2);
    }
}

// ---------- s13: tile sums + word prefix in ONE dispatch; minE init folded ---
// wprefix[w] = exclusive popcount prefix | (any-dup-in-word << 31)
__global__ void __launch_bounds__(256, 2)
k_s13(const u64* __restrict__ bits, const u64* __restrict__ dupb,
      int* __restrict__ tsums, u32* __restrict__ wprefix,
      int* __restrict__ minE, int NK, int* __restrict__ barcnt) {
    __shared__ int s[256];
    __shared__ int tb;
    int tid = threadIdx.x;
    int b = blockIdx.x;
    int gs = gridDim.x * 256;
    for (int i = b * 256 + tid; i < NK; i += gs) minE[i] = 0x7F7F7F7F;

    size_t wb = (size_t)b * 4096 + (size_t)tid * 16;
    int pc[16]; int tsum = 0;
#pragma unroll
    for (int j = 0; j < 16; j++) { pc[j] = __popcll(bits[wb + j]); tsum += pc[j]; }
    s[tid] = tsum; __syncthreads();
    for (int off = 128; off > 0; off >>= 1) {
        if (tid < off) s[tid] += s[tid + off];
        __syncthreads();
    }
    if (tid == 0) tsums[b] = s[0];
    gbar(barcnt, gridDim.x);
    int pre = 0;
    for (int j = tid; j < b; j += 256) pre += tsums[j];
    s[tid] = pre; __syncthreads();
    for (int off = 128; off > 0; off >>= 1) {
        if (tid < off) s[tid] += s[tid + off];
        __syncthreads();
    }
    if (tid == 0) tb = s[0];
    __syncthreads();
    int tbase = tb;
    s[tid] = tsum; __syncthreads();
    for (int off = 1; off < 256; off <<= 1) {
        int t = (tid >= off) ? s[tid - off] : 0;
        __syncthreads();
        s[tid] += t;
        __syncthreads();
    }
    int run = tbase + s[tid] - tsum;
#pragma unroll
    for (int j = 0; j < 16; j++) {
        u32 dup = (dupb[wb + j] != 0ull) ? 0x80000000u : 0u;   // streaming read
        wprefix[wb + j] = (u32)run | dup;
        run += pc[j];
    }
}

// ---------- pass 2: key ids + singleton tile-counts + compact dup list ------
// e0 == 3*idx (n*27 + run*3), so a 256-thread block covers 768 contiguous
// entries -> touches at most 2 bsums tiles.
__global__ void k_kid(const int* __restrict__ si, int N,
                      const u64* __restrict__ bits, const u64* __restrict__ dupb,
                      const u32* __restrict__ wprefix,
                      int* __restrict__ kid, int* __restrict__ minE,
                      int* __restrict__ duplist, int* __restrict__ dupcnt,
                      int* __restrict__ bsums) {
    __shared__ int sc0, sc1, lcnt, lbase;
    int tid = threadIdx.x;
    if (tid == 0) { sc0 = 0; sc1 = 0; lcnt = 0; }
    __syncthreads();
    int idx = blockIdx.x * 256 + tid;
    int mye[3]; int myslot[3]; int mycnt = 0;
    int s0 = 0, s1 = 0;
    int t0 = (blockIdx.x * 768) >> 12;
    if (idx < N * 9) {
        int n = idx / 9, run = idx - n * 9;
        int ox = run / 3, oy = run - ox * 3;
        int b = si[n], x = si[N + n], y = si[2 * N + n], z = si[3 * N + n];
        unsigned enc0 = (unsigned)(((b * S + x + ox) * S + (y + oy)) * S + z);
        unsigned w = enc0 >> 6; int bit = enc0 & 63;
        u64 bw0 = bits[w]; u32 q0 = wprefix[w];
        u64 db0 = (q0 & 0x80000000u) ? dupb[w] : 0ull;    // rare random line
        u64 bw1 = 0, db1 = 0; u32 q1 = 0;
        if (bit > 61) {
            bw1 = bits[w + 1]; q1 = wprefix[w + 1];
            db1 = (q1 & 0x80000000u) ? dupb[w + 1] : 0ull;
        }
        int e0 = idx * 3;
#pragma unroll
        for (int oz = 0; oz < 3; ++oz) {
            unsigned enc = enc0 + oz;
            int bit2 = enc & 63;
            bool hi = (enc >> 6) != w;
            u64 bwx = hi ? bw1 : bw0;
            u64 dbx = hi ? db1 : db0;
            u32 q   = hi ? q1 : q0;
            int kd = (int)(q & 0x7FFFFFFFu) + __popcll(bwx & ((1ull << bit2) - 1));
            int multi = (int)((dbx >> bit2) & 1);
            int e = e0 + oz;
            if (multi) {
                kid[e] = (int)((u32)kd | 0x80000000u);
                atomicMin(&minE[kd], e);                  // ~110k only
                myslot[mycnt] = atomicAdd(&lcnt, 1);      // LDS cursor
                mye[mycnt] = e;
                mycnt++;
            } else {
                kid[e] = kd;
                if ((e >> 12) == t0) s0++; else s1++;
            }
        }
    }
    if (s0) atomicAdd(&sc0, s0);
    if (s1) atomicAdd(&sc1, s1);
    __syncthreads();
    if (tid == 0) {
        if (lcnt) lbase = atomicAdd(dupcnt, lcnt);        // 1 global atomic/block
        if (sc0) atomicAdd(&bsums[t0], sc0);
        if (sc1) atomicAdd(&bsums[t0 + 1], sc1);
    }
    __syncthreads();
    for (int i = 0; i < mycnt; i++) duplist[lbase + myslot[i]] = mye[i];
}

// ---------- fallback dup-first resolver (used only if NB > 768) -------------
__global__ void k_flagB(const int* __restrict__ duplist, const int* __restrict__ dupcnt,
                        const int* __restrict__ kid, const int* __restrict__ minE,
                        u32* __restrict__ dupfirst, int* __restrict__ bsums) {
    int M = *dupcnt;
    int gs = gridDim.x * blockDim.x;
    for (int i = blockIdx.x * blockDim.x + threadIdx.x; i < M; i += gs) {
        int e = duplist[i];
        int kd = kid[e] & 0x7FFFFFFF;
        if (minE[kd] == e) {
            atomicOr(&dupfirst[e >> 5], 1u << (e & 31));
            atomicAdd(&bsums[e >> 12], 1);
        }
    }
}

// ---------- scan C: [dup-first phase + gbar] + scan + ranks + uid in-place --
__global__ void __launch_bounds__(256, 3)
k_scanC(int* __restrict__ kid, const int* __restrict__ duplist,
        const int* __restrict__ dupcnt, const int* __restrict__ minE,
        u32* __restrict__ dupfirst, int* __restrict__ bsums,
        const int* __restrict__ si, int N, int NK, int NB, int fused,
        float* __restrict__ out_key, int* __restrict__ rank_key,
        float4* __restrict__ outF4, int* __restrict__ barcnt) {
    __shared__ int s[256];
    __shared__ u64 s2[256];
    int tid = threadIdx.x;
    int b = blockIdx.x;
    if (fused) {                                   // ~110k items, <=1 per thread
        int M = *dupcnt;
        int gs = gridDim.x * 256;
        for (int i = b * 256 + tid; i < M; i += gs) {
            int e = duplist[i];
            int kd = kid[e] & 0x7FFFFFFF;
            if (minE[kd] == e) {
                atomicOr(&dupfirst[e >> 5], 1u << (e & 31));
                atomicAdd(&bsums[e >> 12], 1);
            }
        }
        gbar(barcnt, gridDim.x);
    }
    // fused scan of bsums: low 32 = exclusive prefix at b, high 32 = total U
    u64 acc = 0;
    for (int j = tid; j < NB; j += 256) {
        u64 v = (u64)(u32)bsums[j];
        acc += v << 32;
        if (j < b) acc += v;
    }
    s2[tid] = acc; __syncthreads();
    for (int off = 128; off > 0; off >>= 1) {
        if (tid < off) s2[tid] += s2[tid + off];
        __syncthreads();
    }
    int blockoff = (int)(u32)(s2[0] & 0xFFFFFFFFull);
    int U = (int)(s2[0] >> 32);

    int base = b * 4096 + tid * 16;
    int kv[16];
    *(int4*)(kv + 0)  = *(const int4*)(kid + base + 0);
    *(int4*)(kv + 4)  = *(const int4*)(kid + base + 4);
    *(int4*)(kv + 8)  = *(const int4*)(kid + base + 8);
    *(int4*)(kv + 12) = *(const int4*)(kid + base + 12);
    // flags: singleton => sign bit clear; dup => dupfirst bitmap (L2-hot)
    u32 dupw = dupfirst[base >> 5];
    int bits16 = (int)((dupw >> ((tid & 1) * 16)) & 0xFFFFu);
    int fbits = 0;
#pragma unroll
    for (int j = 0; j < 16; j++) {
        int e = base + j;
        int f = 0;
        if (e < NK) {
            int v = kv[j];
            f = (v >= 0) ? 1 : ((bits16 >> j) & 1);
        }
        fbits |= f << j;
    }
    int tsum = __popc(fbits);
    s[tid] = tsum; __syncthreads();
    for (int off = 1; off < 256; off <<= 1) {
        int t = (tid >= off) ? s[tid - off] : 0;
        __syncthreads();
        s[tid] += t;
        __syncthreads();
    }
    int offset = blockoff + s[tid] - tsum;
    float4 zf = {0.f, 0.f, 0.f, 0.f};
    int run = 0;
#pragma unroll
    for (int j = 0; j < 16; j++) {
        int e = base + j;
        if ((fbits >> j) & 1) {
            int rank = offset + run;
            int n = e / K; int m = e - n * K;
            int x = si[N + n], y = si[2 * N + n], z = si[3 * N + n];
            int ox = m / 9; int rm = m - ox * 9; int oy = rm / 3; int oz = rm - oy * 3;
            out_key[(size_t)rank * 3 + 0] = (float)(x + ox - 1);
            out_key[(size_t)rank * 3 + 1] = (float)(y + oy - 1);
            out_key[(size_t)rank * 3 + 2] = (float)(z + oz - 1);
            int v = kv[j];
            if (v < 0) {                                  // multi first-entry
                int kd = v & 0x7FFFFFFF;
                rank_key[kd] = rank;
                kid[e] = rank | 0x40000000;               // uid + atomic tag
                float4* q = outF4 + (size_t)rank * 8;     // pre-zero row
#pragma unroll
                for (int q8 = 0; q8 < 8; q8++) q[q8] = zf;
            } else {
                kid[e] = rank;                            // uid, stream tag
            }
            run++;
        }
        // non-flagged dup entries keep kd | 0x80000000 in kid[e]
    }
    // tail rows >= U: outF=0, out_key=-1
    int rows = NK - U;
    int gs2 = gridDim.x * blockDim.x;
    for (int i = b * 256 + tid; i < rows; i += gs2) {
        int row = U + i;
        float4* q = outF4 + (size_t)row * 8;
#pragma unroll
        for (int q8 = 0; q8 < 8; q8++) q[q8] = zf;
        out_key[(size_t)row * 3 + 0] = -1.0f;
        out_key[(size_t)row * 3 + 1] = -1.0f;
        out_key[(size_t)row * 3 + 2] = -1.0f;
    }
}

// ---------- final: kernel_map + feature scatter; uid comes straight from kid
__global__ void k_final(const int* __restrict__ ent, const int* __restrict__ rank_key,
                        const float4* __restrict__ feat4,
                        float* __restrict__ km, float* __restrict__ outF, int NK) {
    int total = NK * 8;
    int gs = gridDim.x * blockDim.x;
    for (int idx = blockIdx.x * blockDim.x + threadIdx.x; idx < total; idx += gs) {
        int e = idx >> 3, g = idx & 7;
        int v = ent[e];                               // 8 lanes same addr
        int n = e / K, m = e - n * K;
        float4 val = feat4[(size_t)n * 8 + g];
        int uid, atom;
        if (v < 0)                { uid = rank_key[v & 0x7FFFFFFF]; atom = 1; }   // dup
        else if (v & 0x40000000)  { uid = v & 0x3FFFFFFF;           atom = 1; }   // multi first
        else                      { uid = v;                        atom = 0; }   // singleton
        float* dst = outF + (size_t)uid * 32 + g * 4;
        if (atom) {
            atomicAdd(dst + 0, val.x);
            atomicAdd(dst + 1, val.y);
            atomicAdd(dst + 2, val.z);
            atomicAdd(dst + 3, val.w);
        } else {
            f4raw vr = {val.x, val.y, val.z, val.w};
            __builtin_nontemporal_store(vr, (f4raw*)dst);   // 346MB write-once stream
        }
        if (g < 3)
            km[(size_t)e * 3 + g] = (g == 0) ? (float)n
                                   : ((g == 1) ? (float)uid : (float)m);
    }
}

extern "C" void kernel_launch(void* const* d_in, const int* in_sizes, int n_in,
                              void* d_out, int out_size, void* d_ws, size_t ws_size,
                              hipStream_t stream) {
    const int* si = (const int*)d_in[0];
    const float4* feat4 = (const float4*)d_in[1];
    int N = in_sizes[0] / 4;
    int NK = N * K;                            // 2,700,000
    int NKp = (NK + 4095) & ~4095;
    int NB = NKp / 4096;                       // 660 (<=768 -> fused scanC)

    int NW = (ENCMAX + 63) / 64;               // 1,073,345 bitmap words
    int NT = (NW + 4095) / 4096;               // 263 tiles (co-resident for gbar)
    int NWp = NT * 4096;

    float* km = (float*)d_out;                 // [NK,3]
    float* out_key = km + (size_t)NK * 3;      // [NK,3]
    float* outF = km + (size_t)NK * 6;         // [NK,32]

    char* w = (char*)d_ws;
    char* p_bar   = w; w += 64;                // 2 barrier counters (zeroed)
    char* p_bits  = w; w += ((size_t)NWp * 8 + 15) & ~(size_t)15;
    char* p_dupb  = w; w += ((size_t)NWp * 8 + 15) & ~(size_t)15;
    char* p_dupf  = w; w += ((size_t)(NKp / 8) + 15) & ~(size_t)15;   // dupfirst bitmap
    char* p_bsums = w; w += ((size_t)(NB + 1) * 4 + 15) & ~(size_t)15;
    char* p_cnt   = w; w += 16;                // duplist cursor
    size_t zbytes = (size_t)(w - (char*)d_ws); // all of the above, one memset
    char* p_tsums = w; w += ((size_t)(NT + 1) * 4 + 15) & ~(size_t)15;
    char* p_wpref = w; w += ((size_t)NWp * 4 + 15) & ~(size_t)15;
    char* p_minE  = w; w += ((size_t)NK * 4 + 15) & ~(size_t)15;
    char* p_kid   = w; w += ((size_t)NKp * 4 + 15) & ~(size_t)15;
    char* p_rank  = w; w += ((size_t)NK * 4 + 15) & ~(size_t)15;
    char* p_dlist = w; w += ((size_t)NK * 4 + 15) & ~(size_t)15;

    int* barcnt   = (int*)p_bar;
    u64* bits     = (u64*)p_bits;
    u64* dupb     = (u64*)p_dupb;
    u32* dupfirst = (u32*)p_dupf;
    int* bsums    = (int*)p_bsums;
    int* dupcnt   = (int*)p_cnt;
    int* tsums    = (int*)p_tsums;
    u32* wprefix  = (u32*)p_wpref;
    int* minE     = (int*)p_minE;
    int* kid      = (int*)p_kid;
    int* rank_key = (int*)p_rank;
    int* duplist  = (int*)p_dlist;

    (void)hipMemsetAsync(d_ws, 0, zbytes, stream);

    int nb9 = (N * 9 + 255) / 256;
    k_mark<<<nb9, 256, 0, stream>>>(si, N, bits, dupb);
    k_s13<<<NT, 256, 0, stream>>>(bits, dupb, tsums, wprefix, minE, NK, barcnt);
    k_kid<<<nb9, 256, 0, stream>>>(si, N, bits, dupb, wprefix, kid, minE,
                                   duplist, dupcnt, bsums);
    int fused = (NB <= 768) ? 1 : 0;
    if (!fused)
        k_flagB<<<256, 256, 0, stream>>>(duplist, dupcnt, kid, minE,
                                         dupfirst, bsums);
    k_scanC<<<NB, 256, 0, stream>>>(kid, duplist, dupcnt, minE, dupfirst,
                                    bsums, si, N, NK, NB, fused,
                                    out_key, rank_key, (float4*)outF,
                                    barcnt + 1);
    k_final<<<4096, 256, 0, stream>>>(kid, rank_key, feat4, km, outF, NK);
}

// Round 8
// 596.583 us; speedup vs baseline: 1.2200x; 1.2200x over previous
//
#include <hip/hip_runtime.h>
#include <stdint.h>

typedef unsigned long long u64;
typedef unsigned u32;
typedef float __attribute__((ext_vector_type(4))) f4raw;

#define K 27
#define S 258
#define ENCMAX (4 * S * S * S)        // 68,694,048 possible keys

// ---- manual grid barrier (used only in k_s13 at NT=263 co-resident blocks) --
__device__ __forceinline__ void gbar(int* cnt, int nblk) {
    __syncthreads();
    if (threadIdx.x == 0) {
        __threadfence();
        __hip_atomic_fetch_add(cnt, 1, __ATOMIC_RELEASE, __HIP_MEMORY_SCOPE_AGENT);
        while (__hip_atomic_load(cnt, __ATOMIC_RELAXED, __HIP_MEMORY_SCOPE_AGENT) < nblk)
            __builtin_amdgcn_s_sleep(2);
        (void)__hip_atomic_load(cnt, __ATOMIC_ACQUIRE, __HIP_MEMORY_SCOPE_AGENT);
        __threadfence();
    }
    __syncthreads();
}

// ---------- pass 1: presence bits + exact dup bits ----------
__global__ void k_mark(const int* __restrict__ si, int N,
                       u64* __restrict__ bits, u64* __restrict__ dupb) {
    int idx = blockIdx.x * blockDim.x + threadIdx.x;
    if (idx >= N * 9) return;
    int n = idx / 9, run = idx - n * 9;
    int ox = run / 3, oy = run - ox * 3;
    int b = si[n], x = si[N + n], y = si[2 * N + n], z = si[3 * N + n];
    unsigned enc0 = (unsigned)(((b * S + x + ox) * S + (y + oy)) * S + z);
    unsigned w = enc0 >> 6; int bit = enc0 & 63;
    u64 m1 = 7ull << bit;
    u64 old = atomicOr(&bits[w], m1);
    u64 d1 = old & m1;
    if (d1) atomicOr(&dupb[w], d1);                 // rare (~55k total)
    if (bit > 61) {
        u64 m2 = 7ull >> (64 - bit);
        u64 old2 = atomicOr(&bits[w + 1], m2);
        u64 d2 = old2 & m2;
        if (d2) atomicOr(&dupb[w + 1], d2);
    }
}

// ---------- s13: tile sums + word prefix in ONE dispatch; minE init folded ---
// wprefix[w] = exclusive popcount prefix | (any-dup-in-word << 31)
__global__ void __launch_bounds__(256, 2)
k_s13(const u64* __restrict__ bits, const u64* __restrict__ dupb,
      int* __restrict__ tsums, u32* __restrict__ wprefix,
      int* __restrict__ minE, int NK, int* __restrict__ barcnt) {
    __shared__ int s[256];
    __shared__ int tb;
    int tid = threadIdx.x;
    int b = blockIdx.x;
    // fold the minE memset in (~40 ints/thread, streaming)
    int gs = gridDim.x * 256;
    for (int i = b * 256 + tid; i < NK; i += gs) minE[i] = 0x7F7F7F7F;

    size_t wb = (size_t)b * 4096 + (size_t)tid * 16;
    int pc[16]; int tsum = 0;
#pragma unroll
    for (int j = 0; j < 16; j++) { pc[j] = __popcll(bits[wb + j]); tsum += pc[j]; }
    s[tid] = tsum; __syncthreads();
    for (int off = 128; off > 0; off >>= 1) {
        if (tid < off) s[tid] += s[tid + off];
        __syncthreads();
    }
    if (tid == 0) tsums[b] = s[0];
    gbar(barcnt, gridDim.x);
    // exclusive prefix over tile sums for tiles < b (L2-hot, <=263 ints)
    int pre = 0;
    for (int j = tid; j < b; j += 256) pre += tsums[j];
    s[tid] = pre; __syncthreads();
    for (int off = 128; off > 0; off >>= 1) {
        if (tid < off) s[tid] += s[tid + off];
        __syncthreads();
    }
    if (tid == 0) tb = s[0];
    __syncthreads();
    int tbase = tb;
    s[tid] = tsum; __syncthreads();
    for (int off = 1; off < 256; off <<= 1) {
        int t = (tid >= off) ? s[tid - off] : 0;
        __syncthreads();
        s[tid] += t;
        __syncthreads();
    }
    int run = tbase + s[tid] - tsum;
#pragma unroll
    for (int j = 0; j < 16; j++) {
        u32 dup = (dupb[wb + j] != 0ull) ? 0x80000000u : 0u;   // streaming read
        wprefix[wb + j] = (u32)run | dup;
        run += pc[j];
    }
}

// ---------- pass 2: dense key id; dupb fetched ONLY for dup-bearing words ----
__global__ void k_kid(const int* __restrict__ si, int N,
                      const u64* __restrict__ bits, const u64* __restrict__ dupb,
                      const u32* __restrict__ wprefix,
                      int* __restrict__ kid, int* __restrict__ minE) {
    int idx = blockIdx.x * blockDim.x + threadIdx.x;
    if (idx >= N * 9) return;
    int n = idx / 9, run = idx - n * 9;
    int ox = run / 3, oy = run - ox * 3;
    int b = si[n], x = si[N + n], y = si[2 * N + n], z = si[3 * N + n];
    unsigned enc0 = (unsigned)(((b * S + x + ox) * S + (y + oy)) * S + z);
    unsigned w = enc0 >> 6; int bit = enc0 & 63;
    u64 bw0 = bits[w]; u32 q0 = wprefix[w];
    u64 db0 = (q0 & 0x80000000u) ? dupb[w] : 0ull;        // rare random line
    u64 bw1 = 0, db1 = 0; u32 q1 = 0;
    if (bit > 61) {                                       // triplet crosses word
        bw1 = bits[w + 1]; q1 = wprefix[w + 1];
        db1 = (q1 & 0x80000000u) ? dupb[w + 1] : 0ull;
    }
    int e0 = n * K + run * 3;
#pragma unroll
    for (int oz = 0; oz < 3; ++oz) {
        unsigned enc = enc0 + oz;
        int bit2 = enc & 63;
        bool hi = (enc >> 6) != w;
        u64 bwx = hi ? bw1 : bw0;
        u64 dbx = hi ? db1 : db0;
        u32 q   = hi ? q1 : q0;
        int kd = (int)(q & 0x7FFFFFFFu) + __popcll(bwx & ((1ull << bit2) - 1));
        int multi = (int)((dbx >> bit2) & 1);
        kid[e0 + oz] = multi ? (int)((u32)kd | 0x80000000u) : kd;
        if (multi) atomicMin(&minE[kd], e0 + oz);         // ~110k only
    }
}

// ---------- pass 3: per-block flag sums (flag free for singletons) ----------
__global__ void k_flagsum(const int* __restrict__ kid, const int* __restrict__ minE,
                          int NK, int* __restrict__ bsums) {
    __shared__ int s[256];
    int tid = threadIdx.x;
    int base = blockIdx.x * 4096 + tid * 16;
    int kv[16];
    *(int4*)(kv + 0)  = *(const int4*)(kid + base + 0);
    *(int4*)(kv + 4)  = *(const int4*)(kid + base + 4);
    *(int4*)(kv + 8)  = *(const int4*)(kid + base + 8);
    *(int4*)(kv + 12) = *(const int4*)(kid + base + 12);
    int sum = 0;
#pragma unroll
    for (int j = 0; j < 16; j++) {
        int e = base + j;
        if (e < NK) {
            int v = kv[j];
            sum += (v >= 0) ? 1 : (minE[v & 0x7FFFFFFF] == e ? 1 : 0);
        }
    }
    s[tid] = sum; __syncthreads();
    for (int off = 128; off > 0; off >>= 1) {
        if (tid < off) s[tid] += s[tid + off];
        __syncthreads();
    }
    if (tid == 0) bsums[blockIdx.x] = s[0];
}

// ---------- scan C: ranks, out_key, uid written IN-PLACE into kid ----------
__global__ void k_scanC(int* __restrict__ kid, const int* __restrict__ minE,
                        const int* __restrict__ bsums, const int* __restrict__ si,
                        int N, int NK, int NB,
                        float* __restrict__ out_key, int* __restrict__ rank_key,
                        float4* __restrict__ outF4) {
    __shared__ int s[256];
    __shared__ u64 s2[256];
    int tid = threadIdx.x;
    // fused scan of bsums: low 32 = exclusive prefix at blockIdx, high 32 = total U
    u64 acc = 0;
    for (int j = tid; j < NB; j += 256) {
        u64 b = (u64)(u32)bsums[j];
        acc += b << 32;
        if (j < (int)blockIdx.x) acc += b;
    }
    s2[tid] = acc; __syncthreads();
    for (int off = 128; off > 0; off >>= 1) {
        if (tid < off) s2[tid] += s2[tid + off];
        __syncthreads();
    }
    int blockoff = (int)(u32)(s2[0] & 0xFFFFFFFFull);
    int U = (int)(s2[0] >> 32);

    int base = blockIdx.x * 4096 + tid * 16;
    int kv[16];
    *(int4*)(kv + 0)  = *(const int4*)(kid + base + 0);
    *(int4*)(kv + 4)  = *(const int4*)(kid + base + 4);
    *(int4*)(kv + 8)  = *(const int4*)(kid + base + 8);
    *(int4*)(kv + 12) = *(const int4*)(kid + base + 12);
    int fbits = 0;
#pragma unroll
    for (int j = 0; j < 16; j++) {
        int e = base + j;
        int f = 0;
        if (e < NK) {
            int v = kv[j];
            f = (v >= 0) ? 1 : (minE[v & 0x7FFFFFFF] == e ? 1 : 0);
        }
        fbits |= f << j;
    }
    int tsum = __popc(fbits);
    s[tid] = tsum; __syncthreads();
    for (int off = 1; off < 256; off <<= 1) {
        int t = (tid >= off) ? s[tid - off] : 0;
        __syncthreads();
        s[tid] += t;
        __syncthreads();
    }
    int offset = blockoff + s[tid] - tsum;
    float4 zf = {0.f, 0.f, 0.f, 0.f};
    int run = 0;
#pragma unroll
    for (int j = 0; j < 16; j++) {
        int e = base + j;
        if ((fbits >> j) & 1) {
            int rank = offset + run;
            int n = e / K; int m = e - n * K;
            int x = si[N + n], y = si[2 * N + n], z = si[3 * N + n];
            int ox = m / 9; int rm = m - ox * 9; int oy = rm / 3; int oz = rm - oy * 3;
            out_key[(size_t)rank * 3 + 0] = (float)(x + ox - 1);
            out_key[(size_t)rank * 3 + 1] = (float)(y + oy - 1);
            out_key[(size_t)rank * 3 + 2] = (float)(z + oz - 1);
            int v = kv[j];
            if (v < 0) {                                  // multi first-entry
                int kd = v & 0x7FFFFFFF;
                rank_key[kd] = rank;
                kid[e] = rank | 0x40000000;               // uid + atomic tag
                float4* q = outF4 + (size_t)rank * 8;     // pre-zero row
#pragma unroll
                for (int q8 = 0; q8 < 8; q8++) q[q8] = zf;
            } else {
                kid[e] = rank;                            // uid, stream tag
            }
            run++;
        }
        // non-flagged dup entries keep kd | 0x80000000 in kid[e]
    }
    // tail rows >= U: outF=0, out_key=-1
    int rows = NK - U;
    int gs = gridDim.x * blockDim.x;
    for (int i = blockIdx.x * blockDim.x + tid; i < rows; i += gs) {
        int row = U + i;
        float4* q = outF4 + (size_t)row * 8;
#pragma unroll
        for (int q8 = 0; q8 < 8; q8++) q[q8] = zf;
        out_key[(size_t)row * 3 + 0] = -1.0f;
        out_key[(size_t)row * 3 + 1] = -1.0f;
        out_key[(size_t)row * 3 + 2] = -1.0f;
    }
}

// ---------- final: kernel_map + feature scatter; uid comes straight from kid
__global__ void k_final(const int* __restrict__ ent, const int* __restrict__ rank_key,
                        const float4* __restrict__ feat4,
                        float* __restrict__ km, float* __restrict__ outF, int NK) {
    int total = NK * 8;
    int gs = gridDim.x * blockDim.x;
    for (int idx = blockIdx.x * blockDim.x + threadIdx.x; idx < total; idx += gs) {
        int e = idx >> 3, g = idx & 7;
        int v = ent[e];                               // 8 lanes same addr
        int n = e / K, m = e - n * K;
        float4 val = feat4[(size_t)n * 8 + g];
        int uid, atom;
        if (v < 0)                { uid = rank_key[v & 0x7FFFFFFF]; atom = 1; }   // dup
        else if (v & 0x40000000)  { uid = v & 0x3FFFFFFF;           atom = 1; }   // multi first
        else                      { uid = v;                        atom = 0; }   // singleton
        float* dst = outF + (size_t)uid * 32 + g * 4;
        if (atom) {
            atomicAdd(dst + 0, val.x);
            atomicAdd(dst + 1, val.y);
            atomicAdd(dst + 2, val.z);
            atomicAdd(dst + 3, val.w);
        } else {
            f4raw vr = {val.x, val.y, val.z, val.w};
            __builtin_nontemporal_store(vr, (f4raw*)dst);   // 346MB write-once stream
        }
        if (g < 3) {                                   // 32MB write-once stream: NT
            float kmv = (g == 0) ? (float)n
                       : ((g == 1) ? (float)uid : (float)m);
            __builtin_nontemporal_store(kmv, &km[(size_t)e * 3 + g]);
        }
    }
}

extern "C" void kernel_launch(void* const* d_in, const int* in_sizes, int n_in,
                              void* d_out, int out_size, void* d_ws, size_t ws_size,
                              hipStream_t stream) {
    const int* si = (const int*)d_in[0];
    const float4* feat4 = (const float4*)d_in[1];
    int N = in_sizes[0] / 4;
    int NK = N * K;                            // 2,700,000
    int NKp = (NK + 4095) & ~4095;
    int NB = NKp / 4096;                       // ~660

    int NW = (ENCMAX + 63) / 64;               // 1,073,345 bitmap words
    int NT = (NW + 4095) / 4096;               // 263 tiles (co-resident for gbar)
    int NWp = NT * 4096;

    float* km = (float*)d_out;                 // [NK,3]
    float* out_key = km + (size_t)NK * 3;      // [NK,3]
    float* outF = km + (size_t)NK * 6;         // [NK,32]

    char* w = (char*)d_ws;
    char* p_bar   = w; w += 64;                // barrier counter (zeroed)
    char* p_bits  = w; w += ((size_t)NWp * 8 + 15) & ~(size_t)15;
    char* p_dupb  = w; w += ((size_t)NWp * 8 + 15) & ~(size_t)15;
    size_t zbytes = (size_t)(w - (char*)d_ws); // bar + bits + dupb, one memset
    char* p_tsums = w; w += ((size_t)(NT + 1) * 4 + 15) & ~(size_t)15;
    char* p_wpref = w; w += ((size_t)NWp * 4 + 15) & ~(size_t)15;
    char* p_minE  = w; w += ((size_t)NK * 4 + 15) & ~(size_t)15;
    char* p_kid   = w; w += ((size_t)NKp * 4 + 15) & ~(size_t)15;
    char* p_rank  = w; w += ((size_t)NK * 4 + 15) & ~(size_t)15;
    char* p_bsums = w; w += ((size_t)(NB + 1) * 4 + 15) & ~(size_t)15;

    int* barcnt   = (int*)p_bar;
    u64* bits     = (u64*)p_bits;
    u64* dupb     = (u64*)p_dupb;
    int* tsums    = (int*)p_tsums;
    u32* wprefix  = (u32*)p_wpref;
    int* minE     = (int*)p_minE;
    int* kid      = (int*)p_kid;
    int* rank_key = (int*)p_rank;
    int* bsums    = (int*)p_bsums;

    (void)hipMemsetAsync(d_ws, 0, zbytes, stream);   // bar + bits + dupb only

    int nb9 = (N * 9 + 255) / 256;
    k_mark<<<nb9, 256, 0, stream>>>(si, N, bits, dupb);
    k_s13<<<NT, 256, 0, stream>>>(bits, dupb, tsums, wprefix, minE, NK, barcnt);
    k_kid<<<nb9, 256, 0, stream>>>(si, N, bits, dupb, wprefix, kid, minE);
    k_flagsum<<<NB, 256, 0, stream>>>(kid, minE, NK, bsums);
    k_scanC<<<NB, 256, 0, stream>>>(kid, minE, bsums, si, N, NK, NB,
                                    out_key, rank_key, (float4*)outF);
    k_final<<<2048, 256, 0, stream>>>(kid, rank_key, feat4, km, outF, NK);
}